// Round 1
// baseline (110.962 us; speedup 1.0000x reference)
//
#include <hip/hip_runtime.h>
#include <math.h>

#define NT 5
#define NB 8
#define NC 32
#define NH 256
#define NW 256
#define NHW (NH * NW)        // 65536
#define NBC (NB * NC)        // 256
#define NTBC (NT * NBC)      // 1280
#define KS 7
#define PAD 3
#define VIS_TH 0.1f

// ---------- helpers ----------

__device__ __forceinline__ void make_k1(float k[KS]) {
    float s = 0.f;
#pragma unroll
    for (int i = 0; i < KS; ++i) {
        float xx = (float)i - 3.0f;
        float t = xx / 1.5f;
        k[i] = expf(-0.5f * t * t);
        s += k[i];
    }
    float inv = 1.0f / s;
#pragma unroll
    for (int i = 0; i < KS; ++i) k[i] *= inv;
}

__device__ __forceinline__ int refl(int z) {
    // reflect (no edge repeat): -1 -> 1, -2 -> 2 ; NH -> NH-2, NH+1 -> NH-3
    z = (z < 0) ? -z : z;
    z = (z >= NH) ? (2 * NH - 2 - z) : z;
    return z;
}

__device__ __forceinline__ float rweight(int y, int r, const float k1[KS]) {
    float s = 0.f;
#pragma unroll
    for (int d = 0; d < KS; ++d) {
        int z = y + d - PAD;
        if (refl(z) == r) s += k1[d];
    }
    return s;
}

// max over y of rweight(y, r): rweight is nonzero only for y in
// [r-3, r+3] U [0, 3-r] (r<=3) U [2*NH-5-r, NH-1] (r>=NH-4); the scan set
// {0..6} U {r-3..r+3} U {NH-7..NH-1} is a superset.
__device__ __forceinline__ float rwmax(int r, const float k1[KS]) {
    float m = 0.f;
#pragma unroll
    for (int y = 0; y < KS; ++y) m = fmaxf(m, rweight(y, r, k1));
    int lo = max(0, r - PAD), hi = min(NH - 1, r + PAD);
    for (int y = lo; y <= hi; ++y) m = fmaxf(m, rweight(y, r, k1));
#pragma unroll
    for (int y = NH - KS; y < NH; ++y) m = fmaxf(m, rweight(y, r, k1));
    return m;
}

// ---------- kernel 1: per-(t,b,c) argmax/max of sigmoid(x)*urnd ----------

__global__ __launch_bounds__(256) void k_argmax(
        const float* __restrict__ x, const float* __restrict__ urnd,
        float* __restrict__ mx_out, int* __restrict__ arg_out) {
    const int row = blockIdx.x;          // t*NBC + bc
    const int bc = row & (NBC - 1);
    const int tid = threadIdx.x;

    const float4* u4 = (const float4*)urnd + (size_t)row * (NHW / 4);
    const float4* x4 = (const float4*)x + (size_t)bc * (NHW / 4);

    float best = -1.f;
    int bidx = 0;

#pragma unroll 4
    for (int j = 0; j < NHW / 4 / 256; ++j) {
        int v = j * 256 + tid;
        float4 uu = u4[v];
        float4 xx = x4[v];
        float s0 = 1.f / (1.f + expf(-xx.x));
        float s1 = 1.f / (1.f + expf(-xx.y));
        float s2 = 1.f / (1.f + expf(-xx.z));
        float s3 = 1.f / (1.f + expf(-xx.w));
        float p0 = s0 * uu.x, p1 = s1 * uu.y, p2 = s2 * uu.z, p3 = s3 * uu.w;
        int p = 4 * v;
        if (p0 > best) { best = p0; bidx = p; }
        if (p1 > best) { best = p1; bidx = p + 1; }
        if (p2 > best) { best = p2; bidx = p + 2; }
        if (p3 > best) { best = p3; bidx = p + 3; }
    }

    __shared__ float sv[256];
    __shared__ int si[256];
    sv[tid] = best;
    si[tid] = bidx;
    __syncthreads();
#pragma unroll
    for (int off = 128; off > 0; off >>= 1) {
        if (tid < off) {
            float ov = sv[tid + off];
            int oi = si[tid + off];
            if (ov > sv[tid] || (ov == sv[tid] && oi < si[tid])) {
                sv[tid] = ov;
                si[tid] = oi;
            }
        }
        __syncthreads();
    }
    if (tid == 0) {
        mx_out[row] = sv[0];
        arg_out[row] = si[0];
    }
}

// ---------- kernel 2: per-(b,c) stats over T, plus global max of blurred att ----------

__global__ __launch_bounds__(256) void k_stats(
        const float* __restrict__ mx, const int* __restrict__ arg,
        float* __restrict__ out_m, float* __restrict__ out_v,
        float* __restrict__ out_vis,
        int* __restrict__ rows_out, int* __restrict__ cols_out,
        int* __restrict__ vis_out, float* __restrict__ gmax_out) {
    const int bc = threadIdx.x;   // 0..255, single block
    float k1[KS];
    make_k1(k1);

    float ji[NT], jj[NT];
    int visn = 0;
#pragma unroll
    for (int t = 0; t < NT; ++t) {
        float m = mx[t * NBC + bc];
        int a = arg[t * NBC + bc];
        bool vt = (m >= VIS_TH);
        float ii = (float)(a >> 8) * (1.0f / (float)NH);
        float jv = (float)(a & (NW - 1)) * (1.0f / (float)NW);
        ji[t] = vt ? ii : 0.f;
        jj[t] = vt ? jv : 0.f;
        visn += vt ? 1 : 0;
    }
    float mi = (ji[0] + ji[1] + ji[2] + ji[3] + ji[4]) / 5.0f;
    float mj = (jj[0] + jj[1] + jj[2] + jj[3] + jj[4]) / 5.0f;
    float vi = 0.f, vj = 0.f;
#pragma unroll
    for (int t = 0; t < NT; ++t) {
        float di = ji[t] - mi, dj = jj[t] - mj;
        vi += di * di;
        vj += dj * dj;
    }
    vi /= (float)(NT - 1);
    vj /= (float)(NT - 1);

    bool vis = (visn >= 3);   // mean(vis_t) > 0.5  <=>  count >= 3 (T=5)

    out_m[bc * 2 + 0] = vis ? mi : 0.f;
    out_m[bc * 2 + 1] = vis ? mj : 0.f;
    out_v[bc * 2 + 0] = vis ? vi : 0.f;
    out_v[bc * 2 + 1] = vis ? vj : 0.f;
    out_vis[bc] = vis ? 1.f : 0.f;

    int r = min(max((int)roundf((vis ? mi : 0.f) * (float)NH), 0), NH - 1);
    int c = min(max((int)roundf((vis ? mj : 0.f) * (float)NW), 0), NW - 1);
    rows_out[bc] = r;
    cols_out[bc] = c;
    vis_out[bc] = vis ? 1 : 0;

    // per-channel max of blurred one-hot = max_y rw(y) * max_x cw(x)
    float cmax = vis ? (rwmax(r, k1) * rwmax(c, k1)) : 0.f;

    __shared__ float gm[256];
    gm[bc] = cmax;
    __syncthreads();
#pragma unroll
    for (int off = 128; off > 0; off >>= 1) {
        if (bc < off) gm[bc] = fmaxf(gm[bc], gm[bc + off]);
        __syncthreads();
    }
    if (bc == 0) gmax_out[0] = gm[0];
}

// ---------- kernel 3: write normalized blurred att directly ----------
// att(y,x) = vis ? rw(y)*cw(x)/gmax : 0    (global min is exactly 0)

__global__ __launch_bounds__(256) void k_att(
        const int* __restrict__ rows, const int* __restrict__ cols,
        const int* __restrict__ visf, const float* __restrict__ gmaxp,
        float* __restrict__ att) {
    const int ROWS_PER_BLK = 16;
    const int bc = blockIdx.x >> 4;                    // NBC * 16 blocks
    const int y0 = (blockIdx.x & 15) * ROWS_PER_BLK;
    const int tid = threadIdx.x;                       // x coordinate

    const int r = rows[bc];
    const int c = cols[bc];
    const int vis = visf[bc];
    const float gmax = gmaxp[0];

    float* out = att + (size_t)bc * NHW;

    if (!vis) {
#pragma unroll
        for (int dy = 0; dy < ROWS_PER_BLK; ++dy)
            out[(y0 + dy) * NW + tid] = 0.f;
        return;
    }

    float k1[KS];
    make_k1(k1);
    const float cw = rweight(tid, c, k1);              // depends on x only

#pragma unroll
    for (int dy = 0; dy < ROWS_PER_BLK; ++dy) {
        int y = y0 + dy;
        float rw = rweight(y, r, k1);
        float raw = rw * cw;
        out[y * NW + tid] = (raw == 0.f) ? 0.f : (raw / gmax);
    }
}

// ---------- launcher ----------

extern "C" void kernel_launch(void* const* d_in, const int* in_sizes, int n_in,
                              void* d_out, int out_size, void* d_ws, size_t ws_size,
                              hipStream_t stream) {
    const float* x = (const float*)d_in[0];
    const float* urnd = (const float*)d_in[1];

    float* out = (float*)d_out;
    float* out_att = out;                        // [8,32,256,256]
    float* out_m = out + (size_t)NBC * NHW;      // [8,32,2]
    float* out_v = out_m + NBC * 2;              // [8,32,2]
    float* out_vis = out_v + NBC * 2;            // [8,32]

    // workspace layout
    char* ws = (char*)d_ws;
    float* mx = (float*)ws;                 ws += NTBC * sizeof(float);
    int* arg = (int*)ws;                    ws += NTBC * sizeof(int);
    int* rows = (int*)ws;                   ws += NBC * sizeof(int);
    int* cols = (int*)ws;                   ws += NBC * sizeof(int);
    int* visf = (int*)ws;                   ws += NBC * sizeof(int);
    float* gmax = (float*)ws;

    k_argmax<<<NTBC, 256, 0, stream>>>(x, urnd, mx, arg);
    k_stats<<<1, 256, 0, stream>>>(mx, arg, out_m, out_v, out_vis,
                                   rows, cols, visf, gmax);
    k_att<<<NBC * 16, 256, 0, stream>>>(rows, cols, visf, gmax, out_att);
}

// Round 2
// 109.321 us; speedup vs baseline: 1.0150x; 1.0150x over previous
//
#include <hip/hip_runtime.h>
#include <math.h>

#define NT 5
#define NB 8
#define NC 32
#define NH 256
#define NW 256
#define NHW (NH * NW)        // 65536
#define NBC (NB * NC)        // 256
#define NTBC (NT * NBC)      // 1280
#define KS 7
#define PAD 3
#define VIS_TH 0.1f

#define HALVES 2
#define EPH (NHW / HALVES)       // elements per half = 32768
#define V4PH (EPH / 4)           // float4 per half = 8192
#define ITER (V4PH / 256)        // 32 iterations per thread

typedef float vf4 __attribute__((ext_vector_type(4)));

// ---------- helpers ----------

__device__ __forceinline__ void make_k1(float k[KS]) {
    float s = 0.f;
#pragma unroll
    for (int i = 0; i < KS; ++i) {
        float xx = (float)i - 3.0f;
        float t = xx / 1.5f;
        k[i] = expf(-0.5f * t * t);
        s += k[i];
    }
    float inv = 1.0f / s;
#pragma unroll
    for (int i = 0; i < KS; ++i) k[i] *= inv;
}

__device__ __forceinline__ int refl(int z) {
    z = (z < 0) ? -z : z;
    z = (z >= NH) ? (2 * NH - 2 - z) : z;
    return z;
}

__device__ __forceinline__ float rweight(int y, int r, const float k1[KS]) {
    float s = 0.f;
#pragma unroll
    for (int d = 0; d < KS; ++d) {
        int z = y + d - PAD;
        if (refl(z) == r) s += k1[d];
    }
    return s;
}

__device__ __forceinline__ float rwmax(int r, const float k1[KS]) {
    float m = 0.f;
#pragma unroll
    for (int y = 0; y < KS; ++y) m = fmaxf(m, rweight(y, r, k1));
    int lo = max(0, r - PAD), hi = min(NH - 1, r + PAD);
    for (int y = lo; y <= hi; ++y) m = fmaxf(m, rweight(y, r, k1));
#pragma unroll
    for (int y = NH - KS; y < NH; ++y) m = fmaxf(m, rweight(y, r, k1));
    return m;
}

// ---------- kernel 1: per-(t,b,c,half) partial argmax/max ----------

__global__ __launch_bounds__(256) void k_argmax(
        const float* __restrict__ x, const float* __restrict__ urnd,
        float* __restrict__ pmx, int* __restrict__ parg) {
    const int blk = blockIdx.x;          // (t*NBC + bc) * 2 + half
    const int row = blk >> 1;
    const int half = blk & 1;
    const int bc = row & (NBC - 1);
    const int tid = threadIdx.x;

    const vf4* u4 = (const vf4*)urnd + (size_t)row * (NHW / 4) + half * V4PH;
    const vf4* x4 = (const vf4*)x + (size_t)bc * (NHW / 4) + half * V4PH;

    // 4 independent running-max chains (one per float4 slot)
    float b0 = -1.f, b1 = -1.f, b2 = -1.f, b3 = -1.f;
    int i0 = 0, i1 = 0, i2 = 0, i3 = 0;

#pragma unroll 8
    for (int j = 0; j < ITER; ++j) {
        int v = j * 256 + tid;
        vf4 uu = __builtin_nontemporal_load(u4 + v);  // streaming, no reuse
        vf4 xx = x4[v];                               // cached, reused 5x
        float s0 = 1.f / (1.f + expf(-xx[0]));
        float s1 = 1.f / (1.f + expf(-xx[1]));
        float s2 = 1.f / (1.f + expf(-xx[2]));
        float s3 = 1.f / (1.f + expf(-xx[3]));
        float p0 = s0 * uu[0], p1 = s1 * uu[1], p2 = s2 * uu[2], p3 = s3 * uu[3];
        int base = v * 4;
        if (p0 > b0) { b0 = p0; i0 = base; }
        if (p1 > b1) { b1 = p1; i1 = base + 1; }
        if (p2 > b2) { b2 = p2; i2 = base + 2; }
        if (p3 > b3) { b3 = p3; i3 = base + 3; }
    }

    // merge the 4 chains; on value tie prefer smaller index (first occurrence)
    float best = b0; int bidx = i0;
    if (b1 > best || (b1 == best && i1 < bidx)) { best = b1; bidx = i1; }
    if (b2 > best || (b2 == best && i2 < bidx)) { best = b2; bidx = i2; }
    if (b3 > best || (b3 == best && i3 < bidx)) { best = b3; bidx = i3; }

    // wave butterfly reduce (64 lanes)
#pragma unroll
    for (int m = 32; m; m >>= 1) {
        float ov = __shfl_xor(best, m, 64);
        int oi = __shfl_xor(bidx, m, 64);
        if (ov > best || (ov == best && oi < bidx)) { best = ov; bidx = oi; }
    }

    __shared__ float sv[4];
    __shared__ int si[4];
    int wid = tid >> 6;
    if ((tid & 63) == 0) { sv[wid] = best; si[wid] = bidx; }
    __syncthreads();
    if (tid == 0) {
#pragma unroll
        for (int w = 1; w < 4; ++w) {
            if (sv[w] > best || (sv[w] == best && si[w] < bidx)) {
                best = sv[w]; bidx = si[w];
            }
        }
        pmx[blk] = best;
        parg[blk] = half * EPH + bidx;   // global index within the row
    }
}

// ---------- kernel 2: fused stats + att write ----------
// 256 blocks (one per bc). Every block redundantly computes all-bc stats
// (10 KB of L2-hit loads) to obtain the global max; block 0 also writes the
// small outputs; every block writes its own 256 KB att plane.

__global__ __launch_bounds__(256) void k_statt(
        const float* __restrict__ pmx, const int* __restrict__ parg,
        float* __restrict__ out_m, float* __restrict__ out_v,
        float* __restrict__ out_vis, float* __restrict__ att) {
    const int tid = threadIdx.x;     // doubles as "bc" for the stats phase
    const int myc = blockIdx.x;      // the bc this block writes

    float k1[KS];
    make_k1(k1);

    // ---- stats for bc = tid ----
    float ji[NT], jj[NT];
    int visn = 0;
#pragma unroll
    for (int t = 0; t < NT; ++t) {
        int r2 = (t * NBC + tid) * 2;
        float m0 = pmx[r2], m1 = pmx[r2 + 1];
        int a0 = parg[r2], a1 = parg[r2 + 1];
        float m = m0; int a = a0;
        if (m1 > m) { m = m1; a = a1; }     // tie -> half 0 (smaller index)
        bool vt = (m >= VIS_TH);
        float ii = (float)(a >> 8) * (1.0f / (float)NH);
        float jv = (float)(a & (NW - 1)) * (1.0f / (float)NW);
        ji[t] = vt ? ii : 0.f;
        jj[t] = vt ? jv : 0.f;
        visn += vt ? 1 : 0;
    }
    float mi = (ji[0] + ji[1] + ji[2] + ji[3] + ji[4]) / 5.0f;
    float mj = (jj[0] + jj[1] + jj[2] + jj[3] + jj[4]) / 5.0f;
    float vi = 0.f, vj = 0.f;
#pragma unroll
    for (int t = 0; t < NT; ++t) {
        float di = ji[t] - mi, dj = jj[t] - mj;
        vi += di * di;
        vj += dj * dj;
    }
    vi /= (float)(NT - 1);
    vj /= (float)(NT - 1);

    bool vis = (visn >= 3);

    if (blockIdx.x == 0) {
        out_m[tid * 2 + 0] = vis ? mi : 0.f;
        out_m[tid * 2 + 1] = vis ? mj : 0.f;
        out_v[tid * 2 + 0] = vis ? vi : 0.f;
        out_v[tid * 2 + 1] = vis ? vj : 0.f;
        out_vis[tid] = vis ? 1.f : 0.f;
    }

    int r = min(max((int)roundf((vis ? mi : 0.f) * (float)NH), 0), NH - 1);
    int c = min(max((int)roundf((vis ? mj : 0.f) * (float)NW), 0), NW - 1);
    float cmax = vis ? (rwmax(r, k1) * rwmax(c, k1)) : 0.f;

    __shared__ int sR[NBC], sC[NBC], sVis[NBC];
    __shared__ float sG[NBC];
    sR[tid] = r; sC[tid] = c; sVis[tid] = vis ? 1 : 0; sG[tid] = cmax;
    __syncthreads();
#pragma unroll
    for (int off = 128; off; off >>= 1) {
        if (tid < off) sG[tid] = fmaxf(sG[tid], sG[tid + off]);
        __syncthreads();
    }
    const float gmax = sG[0];
    const int r_ = sR[myc], c_ = sC[myc], vis_ = sVis[myc];

    vf4* out4 = (vf4*)(att + (size_t)myc * NHW);

    if (!vis_) {
        vf4 z = {0.f, 0.f, 0.f, 0.f};
#pragma unroll 4
        for (int j = 0; j < 64; ++j) out4[j * 256 + tid] = z;
        return;
    }

    // thread tid writes flat float4 indices f = j*256+tid:
    //   row y = f>>6 = j*4 + (tid>>6)  (wave-uniform),
    //   col quad xq = f&63 = tid&63    (j-invariant) -> 4 fixed columns.
    __shared__ float sRW[NH];
    sRW[tid] = rweight(tid, r_, k1);
    const int xq = tid & 63;
    const float cw0 = rweight(4 * xq + 0, c_, k1);
    const float cw1 = rweight(4 * xq + 1, c_, k1);
    const float cw2 = rweight(4 * xq + 2, c_, k1);
    const float cw3 = rweight(4 * xq + 3, c_, k1);
    __syncthreads();

    const int w = tid >> 6;
    for (int j = 0; j < 64; ++j) {
        int y = j * 4 + w;
        float rw = sRW[y];               // wave-uniform broadcast
        vf4 o;
        if (rw == 0.f) {                 // uniform branch: most rows are zero
            o = (vf4){0.f, 0.f, 0.f, 0.f};
        } else {
            float r0 = rw * cw0, r1 = rw * cw1, r2 = rw * cw2, r3 = rw * cw3;
            o[0] = (r0 == 0.f) ? 0.f : (r0 / gmax);
            o[1] = (r1 == 0.f) ? 0.f : (r1 / gmax);
            o[2] = (r2 == 0.f) ? 0.f : (r2 / gmax);
            o[3] = (r3 == 0.f) ? 0.f : (r3 / gmax);
        }
        out4[j * 256 + tid] = o;
    }
}

// ---------- launcher ----------

extern "C" void kernel_launch(void* const* d_in, const int* in_sizes, int n_in,
                              void* d_out, int out_size, void* d_ws, size_t ws_size,
                              hipStream_t stream) {
    const float* x = (const float*)d_in[0];
    const float* urnd = (const float*)d_in[1];

    float* out = (float*)d_out;
    float* out_att = out;                        // [8,32,256,256]
    float* out_m = out + (size_t)NBC * NHW;      // [8,32,2]
    float* out_v = out_m + NBC * 2;              // [8,32,2]
    float* out_vis = out_v + NBC * 2;            // [8,32]

    char* ws = (char*)d_ws;
    float* pmx = (float*)ws;                ws += NTBC * HALVES * sizeof(float);
    int* parg = (int*)ws;

    k_argmax<<<NTBC * HALVES, 256, 0, stream>>>(x, urnd, pmx, parg);
    k_statt<<<NBC, 256, 0, stream>>>(pmx, parg, out_m, out_v, out_vis, out_att);
}